// Round 13
// baseline (243.770 us; speedup 1.0000x reference)
//
#include <hip/hip_runtime.h>
#include <hip/hip_bf16.h>
#include <math.h>

#define NN 50000
#define NE 800000
#define ETOT (NE + NN)      // 850000, self-loops appended after edges
#define CLS 40
#define CLSP 48             // layer-2 channels padded to 48
#define NEG 0.2f
#define MTILES (NN / 16)    // 3125 exact
#define GB1 ((MTILES + 3) / 4)   // 782 gemm blocks
#define PREPB 176           // prep blocks: ceil(45056/256)
#define NBUCK 196           // ceil(50000/256) dst buckets of 256 nodes
#define BCAP 8192           // per-bucket capacity (mean 4352, sd ~64)
#define EB 4096             // edges per bucket_scatter block
#define KAB ((ETOT + EB - 1) / EB)   // 208
#define PERMN (NBUCK * 256) // 50176 perm slots
#define NODEB (PERMN / 4)   // 12544 node-kernel blocks

typedef __hip_bfloat16 bf16;
typedef __attribute__((ext_vector_type(8))) __bf16 bf16x8;
typedef __attribute__((ext_vector_type(4))) float f32x4;
typedef __attribute__((ext_vector_type(2))) float f32x2;
struct U3 { unsigned x, y, z; };   // 12B, 4-aligned

__device__ __forceinline__ bf16x8 cvt8(f32x4 a, f32x4 b) {
    bf16x8 r;
    r[0] = (__bf16)a[0]; r[1] = (__bf16)a[1]; r[2] = (__bf16)a[2]; r[3] = (__bf16)a[3];
    r[4] = (__bf16)b[0]; r[5] = (__bf16)b[1]; r[6] = (__bf16)b[2]; r[7] = (__bf16)b[3];
    return r;
}
__device__ __forceinline__ f32x2 unpk2(unsigned u) {
    f32x2 r;
    r.x = __uint_as_float(u << 16);
    r.y = __uint_as_float(u & 0xffff0000u);
    return r;
}
// packed leaky-relu: v_pk_mul + 2 max (backend may fuse to pk_max)
__device__ __forceinline__ f32x2 leaky2(f32x2 v) {
    f32x2 s = v * NEG;
    f32x2 r;
    r.x = fmaxf(v.x, s.x);
    r.y = fmaxf(v.y, s.y);
    return r;
}

// 256-entry exclusive scan in LDS (4 waves). Returns exclusive prefix of v.
__device__ __forceinline__ unsigned scan256(unsigned v, unsigned* wsum) {
    int t = threadIdx.x;
    int lane = t & 63, w = t >> 6;
    unsigned inc = v;
#pragma unroll
    for (int d = 1; d < 64; d <<= 1) {
        unsigned x = __shfl_up(inc, d);
        if (lane >= d) inc += x;
    }
    if (lane == 63) wsum[w] = inc;
    __syncthreads();
    unsigned woff = 0;
#pragma unroll
    for (int i = 0; i < 4; i++) woff += (i < w) ? wsum[i] : 0;
    return woff + inc - v;
}

// ---- K1: weight prep (fp32->bf16 transposed) + zero bucket cursors. ----
__global__ __launch_bounds__(256) void prep(
        const float* __restrict__ w1l, const float* __restrict__ w1r,
        const float* __restrict__ w2l, const float* __restrict__ w2r,
        bf16* __restrict__ wT1, bf16* __restrict__ wT2,
        int* __restrict__ bcursor) {
    int t = blockIdx.x * 256 + threadIdx.x;
    if (t < NBUCK) bcursor[t] = 0;
    if (t < 2 * 128 * 128) {
        int m = t >> 14;
        int idx = t & 16383;
        int n = idx >> 7, k = idx & 127;
        const float* w = m ? w1r : w1l;
        wT1[t] = __float2bfloat16(w[k * 128 + n]);
    } else if (t < 2 * 128 * 128 + 2 * CLSP * 128) {
        int u = t - 2 * 128 * 128;
        int m = u / (CLSP * 128);
        int idx = u % (CLSP * 128);
        int n = idx >> 7, k = idx & 127;
        const float* w = m ? w2r : w2l;
        wT2[u] = __float2bfloat16((n < CLS) ? w[k * CLS + n] : 0.0f);
    }
}

// ---- K2: GEMM1 dual (xl1,xr1 = x @ w1{l,r})  ||  bucket scatter. ----
__global__ __launch_bounds__(256) void gemm1_scatter(
        const float* __restrict__ x, const bf16* __restrict__ wT,
        bf16* __restrict__ outL, bf16* __restrict__ outR,
        const int* __restrict__ ei, int* __restrict__ bcursor,
        uint2* __restrict__ tmp) {
    __shared__ unsigned hist[256];
    __shared__ unsigned lstart[256];
    __shared__ unsigned lcur[256];
    __shared__ unsigned gbase[256];
    __shared__ unsigned wsum[4];
    __shared__ uint2 binned[EB];
    __shared__ unsigned target[EB];
    if ((int)blockIdx.x < GB1) {
        int wave = threadIdx.x >> 6;
        int lane = threadIdx.x & 63;
        int tile = blockIdx.x * 4 + wave;
        if (tile >= MTILES) return;
        const bf16* wl = wT;
        const bf16* wr = wT + 128 * 128;
        int row0 = tile * 16;
        int l16 = lane & 15, quad = lane >> 4;
        f32x4 z = {0.f, 0.f, 0.f, 0.f};
        f32x4 accl[8], accr[8];
#pragma unroll
        for (int i = 0; i < 8; i++) { accl[i] = z; accr[i] = z; }
        const float* xrow = x + (size_t)(row0 + l16) * 128 + quad * 8;
#pragma unroll
        for (int k0 = 0; k0 < 128; k0 += 32) {
            f32x4 a0 = *reinterpret_cast<const f32x4*>(xrow + k0);
            f32x4 a1v = *reinterpret_cast<const f32x4*>(xrow + k0 + 4);
            bf16x8 a = cvt8(a0, a1v);
#pragma unroll
            for (int ct = 0; ct < 8; ct++) {
                bf16x8 bl = *reinterpret_cast<const bf16x8*>(wl + (ct * 16 + l16) * 128 + k0 + quad * 8);
                bf16x8 br = *reinterpret_cast<const bf16x8*>(wr + (ct * 16 + l16) * 128 + k0 + quad * 8);
                accl[ct] = __builtin_amdgcn_mfma_f32_16x16x32_bf16(a, bl, accl[ct], 0, 0, 0);
                accr[ct] = __builtin_amdgcn_mfma_f32_16x16x32_bf16(a, br, accr[ct], 0, 0, 0);
            }
        }
#pragma unroll
        for (int ct = 0; ct < 8; ct++)
#pragma unroll
            for (int r = 0; r < 4; r++) {
                size_t o = (size_t)(row0 + quad * 4 + r) * 128 + ct * 16 + l16;
                outL[o] = __float2bfloat16(accl[ct][r]);
                outR[o] = __float2bfloat16(accr[ct][r]);
            }
    } else {
        int t = threadIdx.x;
        int e0 = (blockIdx.x - GB1) * EB;
        hist[t] = 0;
        __syncthreads();
        int srcs[16], dsts[16];
#pragma unroll
        for (int i = 0; i < 16; i++) {
            int e = e0 + i * 256 + t;
            if (e < ETOT) {
                int s, d;
                if (e < NE) { s = ei[e]; d = ei[NE + e]; }
                else        { s = d = e - NE; }
                srcs[i] = s; dsts[i] = d;
                atomicAdd(&hist[d >> 8], 1u);
            } else dsts[i] = -1;
        }
        __syncthreads();
        unsigned v = hist[t];
        unsigned excl = scan256(v, wsum);
        lstart[t] = excl;
        lcur[t] = 0;
        __syncthreads();
        if (t < NBUCK && v > 0)
            gbase[t] = (unsigned)atomicAdd(&bcursor[t], (int)v) + (unsigned)t * BCAP;
        __syncthreads();
#pragma unroll
        for (int i = 0; i < 16; i++) {
            int d = dsts[i];
            if (d >= 0) {
                int bk = d >> 8;
                unsigned p = atomicAdd(&lcur[bk], 1u);
                unsigned slot = lstart[bk] + p;
                binned[slot] = make_uint2((unsigned)srcs[i], (unsigned)d);
                target[slot] = gbase[bk] + p;
            }
        }
        __syncthreads();
        int tot = min(EB, ETOT - e0);
        for (int s = t; s < tot; s += 256)
            tmp[target[s]] = binned[s];
    }
}

// ---- KB: per-bucket node sort -> csr_src + start/deg + degree-sorted perm. ----
__global__ __launch_bounds__(256) void bucket_sort(const int* __restrict__ bcursor,
                                                   const uint2* __restrict__ tmp,
                                                   int* __restrict__ csr_src,
                                                   int* __restrict__ startA,
                                                   int* __restrict__ degA,
                                                   unsigned* __restrict__ perm) {
    __shared__ unsigned hist[256];
    __shared__ unsigned lcur[256];
    __shared__ unsigned wsum[4];
    __shared__ unsigned dbase[64];
    __shared__ unsigned dcur[64];
    int b = blockIdx.x, t = threadIdx.x;
    int cnt = bcursor[b];
    hist[t] = 0;
    if (t < 64) dcur[t] = 0;
    __syncthreads();
    const uint2* seg = tmp + (size_t)b * BCAP;
    for (int s = t; s < cnt; s += 256)
        atomicAdd(&hist[seg[s].y & 255], 1u);
    __syncthreads();
    unsigned v = hist[t];
    unsigned excl = scan256(v, wsum);
    lcur[t] = excl;
    int node = b * 256 + t;
    bool real = node < NN;
    if (real) {
        startA[node] = b * BCAP + (int)excl;
        degA[node] = (int)v;
    }
    // --- degree counting-sort within bucket -> perm (fakes land in bin 63) ---
    unsigned dc = real ? min(v, 62u) : 63u;
    atomicAdd(&dcur[dc], 1u);
    __syncthreads();
    if (t < 64) {
        unsigned bv = dcur[t];
        unsigned inc = bv;
#pragma unroll
        for (int d = 1; d < 64; d <<= 1) {
            unsigned xx = __shfl_up(inc, d);
            if ((t & 63) >= d) inc += xx;
        }
        dbase[t] = inc - bv;
        dcur[t] = 0;
    }
    __syncthreads();
    unsigned rank = dbase[dc] + atomicAdd(&dcur[dc], 1u);
    perm[b * 256 + rank] = (unsigned)node;
    // --- csr scatter ---
    int* cbase = csr_src + (size_t)b * BCAP;
    for (int s = t; s < cnt; s += 256) {
        uint2 p = seg[s];                       // L2-hot re-read
        unsigned pos = atomicAdd(&lcur[p.y & 255], 1u);
        cbase[pos] = (int)p.x;
    }
}

// ---- K5: layer 1 fused. One wave/node, 4 edges/batch, 16 lanes/edge. ----
struct L1S { float s; f32x2 acc[4]; };
__device__ __forceinline__ void l1_consume(uint4 u, bool valid, const f32x2* xrf,
                                           const f32x2* a1f, L1S& st) {
    f32x2 x0 = unpk2(u.x), x1 = unpk2(u.y), x2 = unpk2(u.z), x3 = unpk2(u.w);
    f32x2 e2 = a1f[0] * leaky2(x0 + xrf[0]);
    e2 += a1f[1] * leaky2(x1 + xrf[1]);
    e2 += a1f[2] * leaky2(x2 + xrf[2]);
    e2 += a1f[3] * leaky2(x3 + xrf[3]);
    float e = e2.x + e2.y;
    e += __shfl_xor(e, 1);
    e += __shfl_xor(e, 2);          // per-head logit (4-lane quad)
    float w = valid ? __expf(e) : 0.f;
    st.s += w;
    st.acc[0] += w * x0; st.acc[1] += w * x1;
    st.acc[2] += w * x2; st.acc[3] += w * x3;
}

__global__ __launch_bounds__(256) void node_l1(const unsigned* __restrict__ perm,
                                               const int* __restrict__ startA,
                                               const int* __restrict__ degA,
                                               const int* __restrict__ csr_src,
                                               const bf16* __restrict__ xl,
                                               const bf16* __restrict__ xr,
                                               const float* __restrict__ a1,
                                               const float* __restrict__ b1,
                                               bf16* __restrict__ hb) {
    int wid = (blockIdx.x * 256 + threadIdx.x) >> 6;
    unsigned nid = perm[wid];
    if (nid >= NN) return;
    int lane = threadIdx.x & 63;
    int g = lane >> 4, t = lane & 15;
    unsigned cB = (unsigned)t * 16;
    int j0 = startA[nid];
    int deg = degA[nid];
    unsigned rowB = (unsigned)csr_src[j0 + min(lane, deg - 1)] << 8;
    const char* xlb = (const char*)xl;
    uint4 xru = *(const uint4*)((const char*)xr + (nid << 8) + cB);
    f32x2 xrf[4] = {unpk2(xru.x), unpk2(xru.y), unpk2(xru.z), unpk2(xru.w)};
    f32x2 a1f[4];
    {
        f32x4 lo = *reinterpret_cast<const f32x4*>(a1 + t * 8);
        f32x4 hi = *reinterpret_cast<const f32x4*>(a1 + t * 8 + 4);
        a1f[0].x = lo[0]; a1f[0].y = lo[1]; a1f[1].x = lo[2]; a1f[1].y = lo[3];
        a1f[2].x = hi[0]; a1f[2].y = hi[1]; a1f[3].x = hi[2]; a1f[3].y = hi[3];
    }
    L1S st; st.s = 0.f;
#pragma unroll
    for (int k = 0; k < 4; k++) st.acc[k] = (f32x2){0.f, 0.f};
    int lim = min(deg, 64);
    int nb = (deg + 3) >> 2;
    int b = 0;
    for (; (b + 4) * 4 <= lim; b += 4) {
        unsigned o0 = __shfl(rowB, b * 4 + g) + cB;
        unsigned o1 = __shfl(rowB, b * 4 + 4 + g) + cB;
        unsigned o2 = __shfl(rowB, b * 4 + 8 + g) + cB;
        unsigned o3 = __shfl(rowB, b * 4 + 12 + g) + cB;
        uint4 u0 = *(const uint4*)(xlb + o0);
        uint4 u1 = *(const uint4*)(xlb + o1);
        uint4 u2 = *(const uint4*)(xlb + o2);
        uint4 u3 = *(const uint4*)(xlb + o3);
        l1_consume(u0, true, xrf, a1f, st);
        l1_consume(u1, true, xrf, a1f, st);
        l1_consume(u2, true, xrf, a1f, st);
        l1_consume(u3, true, xrf, a1f, st);
    }
    for (; (b + 2) * 4 <= lim; b += 2) {
        unsigned o0 = __shfl(rowB, b * 4 + g) + cB;
        unsigned o1 = __shfl(rowB, b * 4 + 4 + g) + cB;
        uint4 u0 = *(const uint4*)(xlb + o0);
        uint4 u1 = *(const uint4*)(xlb + o1);
        l1_consume(u0, true, xrf, a1f, st);
        l1_consume(u1, true, xrf, a1f, st);
    }
    for (; b < nb; b++) {
        int p = b * 4 + g;
        bool valid = p < deg;
        int pp = valid ? p : deg - 1;
        unsigned o = __shfl(rowB, min(pp, 63)) + cB;
        if (pp >= 64) o = (((unsigned)csr_src[j0 + pp]) << 8) + cB;
        uint4 u = *(const uint4*)(xlb + o);
        l1_consume(u, valid, xrf, a1f, st);
    }
#pragma unroll
    for (int d = 16; d < 64; d <<= 1) {
        st.s += __shfl_xor(st.s, d);
#pragma unroll
        for (int k = 0; k < 4; k++) {
            st.acc[k].x += __shfl_xor(st.acc[k].x, d);
            st.acc[k].y += __shfl_xor(st.acc[k].y, d);
        }
    }
    if (g == 0) {
        float inv = 1.f / st.s;
        unsigned pk[4];
#pragma unroll
        for (int k = 0; k < 4; k++) {
            float o0 = st.acc[k].x * inv + b1[t * 8 + 2 * k];
            float o1 = st.acc[k].y * inv + b1[t * 8 + 2 * k + 1];
            o0 = o0 > 0.f ? o0 : __expf(o0) - 1.f;
            o1 = o1 > 0.f ? o1 : __expf(o1) - 1.f;
            bf16 r0 = __float2bfloat16(o0), r1 = __float2bfloat16(o1);
            pk[k] = (unsigned)*reinterpret_cast<unsigned short*>(&r0) |
                    ((unsigned)*reinterpret_cast<unsigned short*>(&r1) << 16);
        }
        uint4 w4 = {pk[0], pk[1], pk[2], pk[3]};
        *(uint4*)((char*)hb + (nid << 8) + cB) = w4;
    }
}

// ---- K6: GEMM2 dual: xl2p/xr2p = h @ w2{l,r}(128x48 zero-padded), stride 48. ----
__global__ __launch_bounds__(256) void gemm2(const bf16* __restrict__ h,
                                             const bf16* __restrict__ wT,
                                             bf16* __restrict__ outL,
                                             bf16* __restrict__ outR) {
    int wave = threadIdx.x >> 6;
    int lane = threadIdx.x & 63;
    int tile = blockIdx.x * 4 + wave;
    if (tile >= MTILES) return;
    const bf16* wl = wT;
    const bf16* wr = wT + CLSP * 128;
    int row0 = tile * 16;
    int l16 = lane & 15, quad = lane >> 4;
    f32x4 z = {0.f, 0.f, 0.f, 0.f};
    f32x4 accl[3], accr[3];
#pragma unroll
    for (int i = 0; i < 3; i++) { accl[i] = z; accr[i] = z; }
    const bf16* hrow = h + (size_t)(row0 + l16) * 128 + quad * 8;
#pragma unroll
    for (int k0 = 0; k0 < 128; k0 += 32) {
        bf16x8 a = *reinterpret_cast<const bf16x8*>(hrow + k0);
#pragma unroll
        for (int ct = 0; ct < 3; ct++) {
            bf16x8 bl = *reinterpret_cast<const bf16x8*>(wl + (ct * 16 + l16) * 128 + k0 + quad * 8);
            bf16x8 br = *reinterpret_cast<const bf16x8*>(wr + (ct * 16 + l16) * 128 + k0 + quad * 8);
            accl[ct] = __builtin_amdgcn_mfma_f32_16x16x32_bf16(a, bl, accl[ct], 0, 0, 0);
            accr[ct] = __builtin_amdgcn_mfma_f32_16x16x32_bf16(a, br, accr[ct], 0, 0, 0);
        }
    }
#pragma unroll
    for (int ct = 0; ct < 3; ct++)
#pragma unroll
        for (int r = 0; r < 4; r++) {
            size_t o = (size_t)(row0 + quad * 4 + r) * CLSP + ct * 16 + l16;
            outL[o] = __float2bfloat16(accl[ct][r]);
            outR[o] = __float2bfloat16(accr[ct][r]);
        }
}

// ---- K7: layer 2 fused. One wave/node, 8 edges/batch, 8 lanes/edge, 6 ch/lane. ----
struct L2S { float s; f32x2 acc[3]; };
__device__ __forceinline__ void l2_consume(U3 u, bool valid, const f32x2* xrf,
                                           const f32x2* a2f, L2S& st) {
    f32x2 x0 = unpk2(u.x), x1 = unpk2(u.y), x2 = unpk2(u.z);
    f32x2 e2 = a2f[0] * leaky2(x0 + xrf[0]);
    e2 += a2f[1] * leaky2(x1 + xrf[1]);
    e2 += a2f[2] * leaky2(x2 + xrf[2]);
    float e = e2.x + e2.y;
    e += __shfl_xor(e, 1);
    e += __shfl_xor(e, 2);
    e += __shfl_xor(e, 4);          // full 48-ch logit (8-lane group)
    float w = valid ? __expf(e) : 0.f;
    st.s += w;
    st.acc[0] += w * x0; st.acc[1] += w * x1; st.acc[2] += w * x2;
}

__global__ __launch_bounds__(256) void node_l2(const unsigned* __restrict__ perm,
                                               const int* __restrict__ startA,
                                               const int* __restrict__ degA,
                                               const int* __restrict__ csr_src,
                                               const bf16* __restrict__ xl2,
                                               const bf16* __restrict__ xr2,
                                               const float* __restrict__ a2,
                                               const float* __restrict__ b2,
                                               float* __restrict__ out) {
    int wid = (blockIdx.x * 256 + threadIdx.x) >> 6;
    unsigned nid = perm[wid];
    if (nid >= NN) return;
    int lane = threadIdx.x & 63;
    int g = lane >> 3, t = lane & 7;
    unsigned cB = (unsigned)t * 12;
    int j0 = startA[nid];
    int deg = degA[nid];
    unsigned rowB = (unsigned)csr_src[j0 + min(lane, deg - 1)] * 96u;
    const char* xlb = (const char*)xl2;
    U3 xru = *(const U3*)((const char*)xr2 + nid * 96u + cB);
    f32x2 xrf[3] = {unpk2(xru.x), unpk2(xru.y), unpk2(xru.z)};
    int c = t * 6;
    f32x2 a2f[3];
#pragma unroll
    for (int k = 0; k < 3; k++) {
        a2f[k].x = (c + 2 * k < CLS) ? a2[c + 2 * k] : 0.f;
        a2f[k].y = (c + 2 * k + 1 < CLS) ? a2[c + 2 * k + 1] : 0.f;
    }
    L2S st; st.s = 0.f;
#pragma unroll
    for (int k = 0; k < 3; k++) st.acc[k] = (f32x2){0.f, 0.f};
    int lim = min(deg, 64);
    int nb = (deg + 7) >> 3;
    int b = 0;
    for (; (b + 2) * 8 <= lim; b += 2) {
        unsigned o0 = __shfl(rowB, b * 8 + g) + cB;
        unsigned o1 = __shfl(rowB, b * 8 + 8 + g) + cB;
        U3 u0 = *(const U3*)(xlb + o0);
        U3 u1 = *(const U3*)(xlb + o1);
        l2_consume(u0, true, xrf, a2f, st);
        l2_consume(u1, true, xrf, a2f, st);
    }
    for (; b < nb; b++) {
        int p = b * 8 + g;
        bool valid = p < deg;
        int pp = valid ? p : deg - 1;
        unsigned o = __shfl(rowB, min(pp, 63)) + cB;
        if (pp >= 64) o = (unsigned)csr_src[j0 + pp] * 96u + cB;
        U3 u = *(const U3*)(xlb + o);
        l2_consume(u, valid, xrf, a2f, st);
    }
#pragma unroll
    for (int d = 8; d < 64; d <<= 1) {
        st.s += __shfl_xor(st.s, d);
#pragma unroll
        for (int k = 0; k < 3; k++) {
            st.acc[k].x += __shfl_xor(st.acc[k].x, d);
            st.acc[k].y += __shfl_xor(st.acc[k].y, d);
        }
    }
    float inv = 1.f / st.s;
    float q[6];
    float mx = -3e38f;
#pragma unroll
    for (int k = 0; k < 6; k++) {
        bool val = (c + k < CLS);
        float av = (k & 1) ? st.acc[k >> 1].y : st.acc[k >> 1].x;
        q[k] = val ? (av * inv + b2[c + k]) : -3e38f;
        mx = fmaxf(mx, q[k]);
    }
    mx = fmaxf(mx, __shfl_xor(mx, 1));
    mx = fmaxf(mx, __shfl_xor(mx, 2));
    mx = fmaxf(mx, __shfl_xor(mx, 4));
    float se = 0.f;
#pragma unroll
    for (int k = 0; k < 6; k++) if (c + k < CLS) se += __expf(q[k] - mx);
    se += __shfl_xor(se, 1);
    se += __shfl_xor(se, 2);
    se += __shfl_xor(se, 4);
    float ls = mx + __logf(se);
    if (g == 0) {
        float* o = out + (size_t)nid * CLS + c;
#pragma unroll
        for (int k = 0; k < 6; k++)
            if (c + k < CLS) o[k] = q[k] - ls;
    }
}

extern "C" void kernel_launch(void* const* d_in, const int* in_sizes, int n_in,
                              void* d_out, int out_size, void* d_ws, size_t ws_size,
                              hipStream_t stream) {
    const float* x   = (const float*)d_in[0];
    const int*   ei  = (const int*)d_in[1];
    const float* w1l = (const float*)d_in[2];
    const float* w1r = (const float*)d_in[3];
    const float* a1  = (const float*)d_in[4];
    const float* b1  = (const float*)d_in[5];
    const float* w2l = (const float*)d_in[6];
    const float* w2r = (const float*)d_in[7];
    const float* a2  = (const float*)d_in[8];
    const float* b2  = (const float*)d_in[9];
    float* out = (float*)d_out;

    // Workspace layout (total ~68 MB):
    char* base = (char*)d_ws;
    int*      bcursor = (int*)(base + 0);             //       784 B (zeroed by prep)
    int*      startA  = (int*)(base + 1024);          //   200,000 B
    int*      degA    = (int*)(base + 201024);        //   200,000 B
    uint2*    tmp     = (uint2*)(base + 401024);      // 12,845,056 B (NBUCK*BCAP*8)
    int*      csr_src = (int*)(base + 13246080);      //  6,422,528 B (NBUCK*BCAP*4)
    bf16*     xl1     = (bf16*)(base + 19668608);     // 25,600,000 B (xl1|xr1)
    bf16*     hb      = (bf16*)(base + 45268608);     // 12,800,000 B
    bf16*     xl2p    = (bf16*)(base + 58068608);     //  9,600,000 B (xl2p|xr2p, stride 48)
    bf16*     wT1     = (bf16*)(base + 67668608);     //     65,536 B
    bf16*     wT2     = (bf16*)(base + 67734144);     //     24,576 B
    unsigned* perm    = (unsigned*)(base + 67758720); //   200,704 B (PERMN*4)
    bf16* xr1  = xl1 + (size_t)NN * 128;
    bf16* xr2p = xl2p + (size_t)NN * CLSP;

    prep<<<PREPB, 256, 0, stream>>>(w1l, w1r, w2l, w2r, wT1, wT2, bcursor);
    gemm1_scatter<<<GB1 + KAB, 256, 0, stream>>>(x, wT1, xl1, xr1, ei, bcursor, tmp);
    bucket_sort<<<NBUCK, 256, 0, stream>>>(bcursor, tmp, csr_src, startA, degA, perm);
    node_l1<<<NODEB, 256, 0, stream>>>(perm, startA, degA, csr_src, xl1, xr1, a1, b1, hb);
    gemm2<<<GB1, 256, 0, stream>>>(hb, wT2, xl2p, xr2p);
    node_l2<<<NODEB, 256, 0, stream>>>(perm, startA, degA, csr_src, xl2p, xr2p, a2, b2, out);
}

// Round 14
// 241.052 us; speedup vs baseline: 1.0113x; 1.0113x over previous
//
#include <hip/hip_runtime.h>
#include <hip/hip_bf16.h>
#include <math.h>

#define NN 50000
#define NE 800000
#define ETOT (NE + NN)      // 850000, self-loops appended after edges
#define CLS 40
#define CLSP 48             // layer-2 channels padded to 48
#define NEG 0.2f
#define MTILES (NN / 16)    // 3125 exact
#define GB1 ((MTILES + 3) / 4)   // 782 gemm blocks
#define PREPB 176           // prep blocks: ceil(45056/256)
#define NBUCK 196           // ceil(50000/256) dst buckets of 256 nodes
#define BCAP 8192           // per-bucket capacity (mean 4352, sd ~64)
#define EB 4096             // edges per bucket_scatter block
#define KAB ((ETOT + EB - 1) / EB)   // 208

typedef __hip_bfloat16 bf16;
typedef __attribute__((ext_vector_type(8))) __bf16 bf16x8;
typedef __attribute__((ext_vector_type(4))) float f32x4;
typedef __attribute__((ext_vector_type(2))) float f32x2;
struct U3 { unsigned x, y, z; };   // 12B, 4-aligned

__device__ __forceinline__ bf16x8 cvt8(f32x4 a, f32x4 b) {
    bf16x8 r;
    r[0] = (__bf16)a[0]; r[1] = (__bf16)a[1]; r[2] = (__bf16)a[2]; r[3] = (__bf16)a[3];
    r[4] = (__bf16)b[0]; r[5] = (__bf16)b[1]; r[6] = (__bf16)b[2]; r[7] = (__bf16)b[3];
    return r;
}
// cheap bf16-pair unpack: lo exact; hi keeps the neighbor's 16 bits as mantissa
// noise (<=2^-9 relative — same order as bf16 rounding; inputs finite so no NaN).
__device__ __forceinline__ f32x2 unpk2c(unsigned u) {
    f32x2 r;
    r.x = __uint_as_float(u << 16);
    r.y = __uint_as_float(u);
    return r;
}
// packed leaky-relu: pk_mul + pk_max
__device__ __forceinline__ f32x2 leaky2(f32x2 v) {
    f32x2 s = v * NEG;
    f32x2 r;
    r.x = fmaxf(v.x, s.x);
    r.y = fmaxf(v.y, s.y);
    return r;
}

// 256-entry exclusive scan in LDS (4 waves). Returns exclusive prefix of v.
__device__ __forceinline__ unsigned scan256(unsigned v, unsigned* wsum) {
    int t = threadIdx.x;
    int lane = t & 63, w = t >> 6;
    unsigned inc = v;
#pragma unroll
    for (int d = 1; d < 64; d <<= 1) {
        unsigned x = __shfl_up(inc, d);
        if (lane >= d) inc += x;
    }
    if (lane == 63) wsum[w] = inc;
    __syncthreads();
    unsigned woff = 0;
#pragma unroll
    for (int i = 0; i < 4; i++) woff += (i < w) ? wsum[i] : 0;
    return woff + inc - v;
}

// ---- K1: weight prep (fp32->bf16 transposed) + zero bucket cursors. ----
__global__ __launch_bounds__(256) void prep(
        const float* __restrict__ w1l, const float* __restrict__ w1r,
        const float* __restrict__ w2l, const float* __restrict__ w2r,
        bf16* __restrict__ wT1, bf16* __restrict__ wT2,
        int* __restrict__ bcursor) {
    int t = blockIdx.x * 256 + threadIdx.x;
    if (t < NBUCK) bcursor[t] = 0;
    if (t < 2 * 128 * 128) {
        int m = t >> 14;
        int idx = t & 16383;
        int n = idx >> 7, k = idx & 127;
        const float* w = m ? w1r : w1l;
        wT1[t] = __float2bfloat16(w[k * 128 + n]);
    } else if (t < 2 * 128 * 128 + 2 * CLSP * 128) {
        int u = t - 2 * 128 * 128;
        int m = u / (CLSP * 128);
        int idx = u % (CLSP * 128);
        int n = idx >> 7, k = idx & 127;
        const float* w = m ? w2r : w2l;
        wT2[u] = __float2bfloat16((n < CLS) ? w[k * CLS + n] : 0.0f);
    }
}

// ---- K2: GEMM1 dual (xl1,xr1 = x @ w1{l,r})  ||  bucket scatter. ----
__global__ __launch_bounds__(256) void gemm1_scatter(
        const float* __restrict__ x, const bf16* __restrict__ wT,
        bf16* __restrict__ outL, bf16* __restrict__ outR,
        const int* __restrict__ ei, int* __restrict__ bcursor,
        uint2* __restrict__ tmp) {
    __shared__ unsigned hist[256];
    __shared__ unsigned lstart[256];
    __shared__ unsigned lcur[256];
    __shared__ unsigned gbase[256];
    __shared__ unsigned wsum[4];
    __shared__ uint2 binned[EB];
    __shared__ unsigned target[EB];
    if ((int)blockIdx.x < GB1) {
        int wave = threadIdx.x >> 6;
        int lane = threadIdx.x & 63;
        int tile = blockIdx.x * 4 + wave;
        if (tile >= MTILES) return;
        const bf16* wl = wT;
        const bf16* wr = wT + 128 * 128;
        int row0 = tile * 16;
        int l16 = lane & 15, quad = lane >> 4;
        f32x4 z = {0.f, 0.f, 0.f, 0.f};
        f32x4 accl[8], accr[8];
#pragma unroll
        for (int i = 0; i < 8; i++) { accl[i] = z; accr[i] = z; }
        const float* xrow = x + (size_t)(row0 + l16) * 128 + quad * 8;
#pragma unroll
        for (int k0 = 0; k0 < 128; k0 += 32) {
            f32x4 a0 = *reinterpret_cast<const f32x4*>(xrow + k0);
            f32x4 a1v = *reinterpret_cast<const f32x4*>(xrow + k0 + 4);
            bf16x8 a = cvt8(a0, a1v);
#pragma unroll
            for (int ct = 0; ct < 8; ct++) {
                bf16x8 bl = *reinterpret_cast<const bf16x8*>(wl + (ct * 16 + l16) * 128 + k0 + quad * 8);
                bf16x8 br = *reinterpret_cast<const bf16x8*>(wr + (ct * 16 + l16) * 128 + k0 + quad * 8);
                accl[ct] = __builtin_amdgcn_mfma_f32_16x16x32_bf16(a, bl, accl[ct], 0, 0, 0);
                accr[ct] = __builtin_amdgcn_mfma_f32_16x16x32_bf16(a, br, accr[ct], 0, 0, 0);
            }
        }
#pragma unroll
        for (int ct = 0; ct < 8; ct++)
#pragma unroll
            for (int r = 0; r < 4; r++) {
                size_t o = (size_t)(row0 + quad * 4 + r) * 128 + ct * 16 + l16;
                outL[o] = __float2bfloat16(accl[ct][r]);
                outR[o] = __float2bfloat16(accr[ct][r]);
            }
    } else {
        int t = threadIdx.x;
        int e0 = (blockIdx.x - GB1) * EB;
        hist[t] = 0;
        __syncthreads();
        int srcs[16], dsts[16];
#pragma unroll
        for (int i = 0; i < 16; i++) {
            int e = e0 + i * 256 + t;
            if (e < ETOT) {
                int s, d;
                if (e < NE) { s = ei[e]; d = ei[NE + e]; }
                else        { s = d = e - NE; }
                srcs[i] = s; dsts[i] = d;
                atomicAdd(&hist[d >> 8], 1u);
            } else dsts[i] = -1;
        }
        __syncthreads();
        unsigned v = hist[t];
        unsigned excl = scan256(v, wsum);
        lstart[t] = excl;
        lcur[t] = 0;
        __syncthreads();
        if (t < NBUCK && v > 0)
            gbase[t] = (unsigned)atomicAdd(&bcursor[t], (int)v) + (unsigned)t * BCAP;
        __syncthreads();
#pragma unroll
        for (int i = 0; i < 16; i++) {
            int d = dsts[i];
            if (d >= 0) {
                int bk = d >> 8;
                unsigned p = atomicAdd(&lcur[bk], 1u);
                unsigned slot = lstart[bk] + p;
                binned[slot] = make_uint2((unsigned)srcs[i], (unsigned)d);
                target[slot] = gbase[bk] + p;
            }
        }
        __syncthreads();
        int tot = min(EB, ETOT - e0);
        for (int s = t; s < tot; s += 256)
            tmp[target[s]] = binned[s];
    }
}

// ---- KB: per-bucket node sort -> csr_src + start/deg. One block per bucket. ----
__global__ __launch_bounds__(256) void bucket_sort(const int* __restrict__ bcursor,
                                                   const uint2* __restrict__ tmp,
                                                   int* __restrict__ csr_src,
                                                   int* __restrict__ startA,
                                                   int* __restrict__ degA) {
    __shared__ unsigned hist[256];
    __shared__ unsigned lcur[256];
    __shared__ unsigned wsum[4];
    int b = blockIdx.x, t = threadIdx.x;
    int cnt = bcursor[b];
    hist[t] = 0;
    __syncthreads();
    const uint2* seg = tmp + (size_t)b * BCAP;
    for (int s = t; s < cnt; s += 256)
        atomicAdd(&hist[seg[s].y & 255], 1u);
    __syncthreads();
    unsigned v = hist[t];
    unsigned excl = scan256(v, wsum);
    lcur[t] = excl;
    int node = b * 256 + t;
    if (node < NN) {
        startA[node] = b * BCAP + (int)excl;
        degA[node] = (int)v;
    }
    __syncthreads();
    int* cbase = csr_src + (size_t)b * BCAP;
    for (int s = t; s < cnt; s += 256) {
        uint2 p = seg[s];                       // L2-hot re-read
        unsigned pos = atomicAdd(&lcur[p.y & 255], 1u);
        cbase[pos] = (int)p.x;
    }
}

// ---- K5: layer 1 fused. One wave/node, 4 edges/batch, 16 lanes/edge. ----
struct L1S { float s; f32x2 acc[4]; };
__device__ __forceinline__ void l1_consume(uint4 u, bool valid, const f32x2* xrf,
                                           const f32x2* a1f, L1S& st) {
    f32x2 x0 = unpk2c(u.x), x1 = unpk2c(u.y), x2 = unpk2c(u.z), x3 = unpk2c(u.w);
    f32x2 e2 = a1f[0] * leaky2(x0 + xrf[0]);
    e2 += a1f[1] * leaky2(x1 + xrf[1]);
    e2 += a1f[2] * leaky2(x2 + xrf[2]);
    e2 += a1f[3] * leaky2(x3 + xrf[3]);
    float e = e2.x + e2.y;
    e += __shfl_xor(e, 1);
    e += __shfl_xor(e, 2);          // per-head logit (4-lane quad)
    float w = valid ? __expf(e) : 0.f;
    st.s += w;
    st.acc[0] += w * x0; st.acc[1] += w * x1;
    st.acc[2] += w * x2; st.acc[3] += w * x3;
}

__global__ __launch_bounds__(256) void node_l1(const int* __restrict__ startA,
                                               const int* __restrict__ degA,
                                               const int* __restrict__ csr_src,
                                               const bf16* __restrict__ xl,
                                               const bf16* __restrict__ xr,
                                               const float* __restrict__ a1,
                                               const float* __restrict__ b1,
                                               bf16* __restrict__ hb) {
    int wid = (blockIdx.x * 256 + threadIdx.x) >> 6;
    int lane = threadIdx.x & 63;
    int g = lane >> 4, t = lane & 15;
    unsigned cB = (unsigned)t * 16;
    int j0 = startA[wid];
    int deg = degA[wid];
    unsigned rowB = (unsigned)csr_src[j0 + min(lane, deg - 1)] << 8;
    const char* xlb = (const char*)xl;
    uint4 xru = *(const uint4*)((const char*)xr + ((unsigned)wid << 8) + cB);
    f32x2 xrf[4] = {unpk2c(xru.x), unpk2c(xru.y), unpk2c(xru.z), unpk2c(xru.w)};
    f32x2 a1f[4];
    {
        f32x4 lo = *reinterpret_cast<const f32x4*>(a1 + t * 8);
        f32x4 hi = *reinterpret_cast<const f32x4*>(a1 + t * 8 + 4);
        a1f[0].x = lo[0]; a1f[0].y = lo[1]; a1f[1].x = lo[2]; a1f[1].y = lo[3];
        a1f[2].x = hi[0]; a1f[2].y = hi[1]; a1f[3].x = hi[2]; a1f[3].y = hi[3];
    }
    L1S st; st.s = 0.f;
#pragma unroll
    for (int k = 0; k < 4; k++) st.acc[k] = (f32x2){0.f, 0.f};
    int lim = min(deg, 64);
    int nb = (deg + 3) >> 2;
    int b = 0;
    for (; (b + 4) * 4 <= lim; b += 4) {    // 4 batches (16 edges) in flight
        unsigned o0 = __shfl(rowB, b * 4 + g) + cB;
        unsigned o1 = __shfl(rowB, b * 4 + 4 + g) + cB;
        unsigned o2 = __shfl(rowB, b * 4 + 8 + g) + cB;
        unsigned o3 = __shfl(rowB, b * 4 + 12 + g) + cB;
        uint4 u0 = *(const uint4*)(xlb + o0);
        uint4 u1 = *(const uint4*)(xlb + o1);
        uint4 u2 = *(const uint4*)(xlb + o2);
        uint4 u3 = *(const uint4*)(xlb + o3);
        l1_consume(u0, true, xrf, a1f, st);
        l1_consume(u1, true, xrf, a1f, st);
        l1_consume(u2, true, xrf, a1f, st);
        l1_consume(u3, true, xrf, a1f, st);
    }
    for (; (b + 2) * 4 <= lim; b += 2) {
        unsigned o0 = __shfl(rowB, b * 4 + g) + cB;
        unsigned o1 = __shfl(rowB, b * 4 + 4 + g) + cB;
        uint4 u0 = *(const uint4*)(xlb + o0);
        uint4 u1 = *(const uint4*)(xlb + o1);
        l1_consume(u0, true, xrf, a1f, st);
        l1_consume(u1, true, xrf, a1f, st);
    }
    for (; b < nb; b++) {                   // masked tail (+deg>64 fallback)
        int p = b * 4 + g;
        bool valid = p < deg;
        int pp = valid ? p : deg - 1;
        unsigned o = __shfl(rowB, min(pp, 63)) + cB;
        if (pp >= 64) o = (((unsigned)csr_src[j0 + pp]) << 8) + cB;
        uint4 u = *(const uint4*)(xlb + o);
        l1_consume(u, valid, xrf, a1f, st);
    }
#pragma unroll
    for (int d = 16; d < 64; d <<= 1) {
        st.s += __shfl_xor(st.s, d);
#pragma unroll
        for (int k = 0; k < 4; k++) {
            st.acc[k].x += __shfl_xor(st.acc[k].x, d);
            st.acc[k].y += __shfl_xor(st.acc[k].y, d);
        }
    }
    if (g == 0) {
        float inv = 1.f / st.s;
        unsigned pk[4];
#pragma unroll
        for (int k = 0; k < 4; k++) {
            float o0 = st.acc[k].x * inv + b1[t * 8 + 2 * k];
            float o1 = st.acc[k].y * inv + b1[t * 8 + 2 * k + 1];
            o0 = o0 > 0.f ? o0 : __expf(o0) - 1.f;
            o1 = o1 > 0.f ? o1 : __expf(o1) - 1.f;
            bf16 r0 = __float2bfloat16(o0), r1 = __float2bfloat16(o1);
            pk[k] = (unsigned)*reinterpret_cast<unsigned short*>(&r0) |
                    ((unsigned)*reinterpret_cast<unsigned short*>(&r1) << 16);
        }
        uint4 w4 = {pk[0], pk[1], pk[2], pk[3]};
        *(uint4*)((char*)hb + ((unsigned)wid << 8) + cB) = w4;
    }
}

// ---- K6: GEMM2 dual: xl2p/xr2p = h @ w2{l,r}(128x48 zero-padded), stride 48. ----
__global__ __launch_bounds__(256) void gemm2(const bf16* __restrict__ h,
                                             const bf16* __restrict__ wT,
                                             bf16* __restrict__ outL,
                                             bf16* __restrict__ outR) {
    int wave = threadIdx.x >> 6;
    int lane = threadIdx.x & 63;
    int tile = blockIdx.x * 4 + wave;
    if (tile >= MTILES) return;
    const bf16* wl = wT;
    const bf16* wr = wT + CLSP * 128;
    int row0 = tile * 16;
    int l16 = lane & 15, quad = lane >> 4;
    f32x4 z = {0.f, 0.f, 0.f, 0.f};
    f32x4 accl[3], accr[3];
#pragma unroll
    for (int i = 0; i < 3; i++) { accl[i] = z; accr[i] = z; }
    const bf16* hrow = h + (size_t)(row0 + l16) * 128 + quad * 8;
#pragma unroll
    for (int k0 = 0; k0 < 128; k0 += 32) {
        bf16x8 a = *reinterpret_cast<const bf16x8*>(hrow + k0);
#pragma unroll
        for (int ct = 0; ct < 3; ct++) {
            bf16x8 bl = *reinterpret_cast<const bf16x8*>(wl + (ct * 16 + l16) * 128 + k0 + quad * 8);
            bf16x8 br = *reinterpret_cast<const bf16x8*>(wr + (ct * 16 + l16) * 128 + k0 + quad * 8);
            accl[ct] = __builtin_amdgcn_mfma_f32_16x16x32_bf16(a, bl, accl[ct], 0, 0, 0);
            accr[ct] = __builtin_amdgcn_mfma_f32_16x16x32_bf16(a, br, accr[ct], 0, 0, 0);
        }
    }
#pragma unroll
    for (int ct = 0; ct < 3; ct++)
#pragma unroll
        for (int r = 0; r < 4; r++) {
            size_t o = (size_t)(row0 + quad * 4 + r) * CLSP + ct * 16 + l16;
            outL[o] = __float2bfloat16(accl[ct][r]);
            outR[o] = __float2bfloat16(accr[ct][r]);
        }
}

// ---- K7: layer 2 fused. One wave/node, 8 edges/batch, 8 lanes/edge, 6 ch/lane. ----
struct L2S { float s; f32x2 acc[3]; };
__device__ __forceinline__ void l2_consume(U3 u, bool valid, const f32x2* xrf,
                                           const f32x2* a2f, L2S& st) {
    f32x2 x0 = unpk2c(u.x), x1 = unpk2c(u.y), x2 = unpk2c(u.z);
    f32x2 e2 = a2f[0] * leaky2(x0 + xrf[0]);
    e2 += a2f[1] * leaky2(x1 + xrf[1]);
    e2 += a2f[2] * leaky2(x2 + xrf[2]);
    float e = e2.x + e2.y;
    e += __shfl_xor(e, 1);
    e += __shfl_xor(e, 2);
    e += __shfl_xor(e, 4);          // full 48-ch logit (8-lane group)
    float w = valid ? __expf(e) : 0.f;
    st.s += w;
    st.acc[0] += w * x0; st.acc[1] += w * x1; st.acc[2] += w * x2;
}

__global__ __launch_bounds__(256) void node_l2(const int* __restrict__ startA,
                                               const int* __restrict__ degA,
                                               const int* __restrict__ csr_src,
                                               const bf16* __restrict__ xl2,
                                               const bf16* __restrict__ xr2,
                                               const float* __restrict__ a2,
                                               const float* __restrict__ b2,
                                               float* __restrict__ out) {
    int wid = (blockIdx.x * 256 + threadIdx.x) >> 6;
    int lane = threadIdx.x & 63;
    int g = lane >> 3, t = lane & 7;
    unsigned cB = (unsigned)t * 12;
    int j0 = startA[wid];
    int deg = degA[wid];
    unsigned rowB = (unsigned)csr_src[j0 + min(lane, deg - 1)] * 96u;
    const char* xlb = (const char*)xl2;
    U3 xru = *(const U3*)((const char*)xr2 + (unsigned)wid * 96u + cB);
    f32x2 xrf[3] = {unpk2c(xru.x), unpk2c(xru.y), unpk2c(xru.z)};
    int c = t * 6;
    f32x2 a2f[3];
#pragma unroll
    for (int k = 0; k < 3; k++) {
        a2f[k].x = (c + 2 * k < CLS) ? a2[c + 2 * k] : 0.f;
        a2f[k].y = (c + 2 * k + 1 < CLS) ? a2[c + 2 * k + 1] : 0.f;
    }
    L2S st; st.s = 0.f;
#pragma unroll
    for (int k = 0; k < 3; k++) st.acc[k] = (f32x2){0.f, 0.f};
    int lim = min(deg, 64);
    int nb = (deg + 7) >> 3;
    int b = 0;
    for (; (b + 2) * 8 <= lim; b += 2) {
        unsigned o0 = __shfl(rowB, b * 8 + g) + cB;
        unsigned o1 = __shfl(rowB, b * 8 + 8 + g) + cB;
        U3 u0 = *(const U3*)(xlb + o0);
        U3 u1 = *(const U3*)(xlb + o1);
        l2_consume(u0, true, xrf, a2f, st);
        l2_consume(u1, true, xrf, a2f, st);
    }
    for (; b < nb; b++) {
        int p = b * 8 + g;
        bool valid = p < deg;
        int pp = valid ? p : deg - 1;
        unsigned o = __shfl(rowB, min(pp, 63)) + cB;
        if (pp >= 64) o = (unsigned)csr_src[j0 + pp] * 96u + cB;
        U3 u = *(const U3*)(xlb + o);
        l2_consume(u, valid, xrf, a2f, st);
    }
#pragma unroll
    for (int d = 8; d < 64; d <<= 1) {
        st.s += __shfl_xor(st.s, d);
#pragma unroll
        for (int k = 0; k < 3; k++) {
            st.acc[k].x += __shfl_xor(st.acc[k].x, d);
            st.acc[k].y += __shfl_xor(st.acc[k].y, d);
        }
    }
    float inv = 1.f / st.s;
    float q[6];
    float mx = -3e38f;
#pragma unroll
    for (int k = 0; k < 6; k++) {
        bool val = (c + k < CLS);
        float av = (k & 1) ? st.acc[k >> 1].y : st.acc[k >> 1].x;
        q[k] = val ? (av * inv + b2[c + k]) : -3e38f;
        mx = fmaxf(mx, q[k]);
    }
    mx = fmaxf(mx, __shfl_xor(mx, 1));
    mx = fmaxf(mx, __shfl_xor(mx, 2));
    mx = fmaxf(mx, __shfl_xor(mx, 4));
    float se = 0.f;
#pragma unroll
    for (int k = 0; k < 6; k++) if (c + k < CLS) se += __expf(q[k] - mx);
    se += __shfl_xor(se, 1);
    se += __shfl_xor(se, 2);
    se += __shfl_xor(se, 4);
    float ls = mx + __logf(se);
    if (g == 0) {
        float* o = out + (size_t)wid * CLS + c;
#pragma unroll
        for (int k = 0; k < 6; k++)
            if (c + k < CLS) o[k] = q[k] - ls;
    }
}

extern "C" void kernel_launch(void* const* d_in, const int* in_sizes, int n_in,
                              void* d_out, int out_size, void* d_ws, size_t ws_size,
                              hipStream_t stream) {
    const float* x   = (const float*)d_in[0];
    const int*   ei  = (const int*)d_in[1];
    const float* w1l = (const float*)d_in[2];
    const float* w1r = (const float*)d_in[3];
    const float* a1  = (const float*)d_in[4];
    const float* b1  = (const float*)d_in[5];
    const float* w2l = (const float*)d_in[6];
    const float* w2r = (const float*)d_in[7];
    const float* a2  = (const float*)d_in[8];
    const float* b2  = (const float*)d_in[9];
    float* out = (float*)d_out;

    // Workspace layout (total ~67.8 MB):
    char* base = (char*)d_ws;
    int*   bcursor = (int*)(base + 0);             //       784 B (zeroed by prep)
    int*   startA  = (int*)(base + 1024);          //   200,000 B
    int*   degA    = (int*)(base + 201024);        //   200,000 B
    uint2* tmp     = (uint2*)(base + 401024);      // 12,845,056 B (NBUCK*BCAP*8)
    int*   csr_src = (int*)(base + 13246080);      //  6,422,528 B (NBUCK*BCAP*4)
    bf16*  xl1     = (bf16*)(base + 19668608);     // 25,600,000 B (xl1|xr1)
    bf16*  hb      = (bf16*)(base + 45268608);     // 12,800,000 B
    bf16*  xl2p    = (bf16*)(base + 58068608);     //  9,600,000 B (xl2p|xr2p, stride 48)
    bf16*  wT1     = (bf16*)(base + 67668608);     //     65,536 B
    bf16*  wT2     = (bf16*)(base + 67734144);     //     24,576 B
    bf16* xr1  = xl1 + (size_t)NN * 128;
    bf16* xr2p = xl2p + (size_t)NN * CLSP;

    prep<<<PREPB, 256, 0, stream>>>(w1l, w1r, w2l, w2r, wT1, wT2, bcursor);
    gemm1_scatter<<<GB1 + KAB, 256, 0, stream>>>(x, wT1, xl1, xr1, ei, bcursor, tmp);
    bucket_sort<<<NBUCK, 256, 0, stream>>>(bcursor, tmp, csr_src, startA, degA);
    node_l1<<<(NN * 64) / 256, 256, 0, stream>>>(startA, degA, csr_src, xl1, xr1, a1, b1, hb);
    gemm2<<<GB1, 256, 0, stream>>>(hb, wT2, xl2p, xr2p);
    node_l2<<<(NN * 64) / 256, 256, 0, stream>>>(startA, degA, csr_src, xl2p, xr2p, a2, b2, out);
}